// Round 2
// baseline (5058.002 us; speedup 1.0000x reference)
//
#include <hip/hip_runtime.h>
#include <cstdint>

#define Bb 64
#define Tt 4096
#define Dd 67
#define Hh 128

typedef _Float16 f16;
typedef _Float16 half8 __attribute__((ext_vector_type(8)));
typedef float f32x4 __attribute__((ext_vector_type(4)));

#define MFMA16(A,B,C) __builtin_amdgcn_mfma_f32_16x16x32_f16((A),(B),(C),0,0,0)

static __device__ __forceinline__ float fast_rcp(float x){ return __builtin_amdgcn_rcpf(x); }
static __device__ __forceinline__ float fast_ex2(float x){ return __builtin_amdgcn_exp2f(x); }
#define L2E  1.442695041f
#define L2E2 2.885390082f

union U2 { uint2 u; f16 h[4]; };
union U1 { unsigned u; f16 h[2]; };

__device__ __forceinline__ void red2(float& s, float& q){
#pragma unroll
  for (int off = 32; off; off >>= 1){ s += __shfl_xor(s, off); q += __shfl_xor(q, off); }
}

// ---------------------------------------------------------------------------
// Stage A: LN(67) -> MFMA proj -> LN(128)+SiLU -> MFMA GEMM2 -> z fp16 to
// d_ws in layout [b][t][512] with zoff(j,g) = (j>>5)*128+(j&15)*8+((j>>4)&1)*4+g.
// (unchanged from verified v7)
// ---------------------------------------------------------------------------
__global__ __launch_bounds__(512, 2)
void stage_a(const float* __restrict__ x,
             const float* __restrict__ g_in, const float* __restrict__ b_in,
             const float* __restrict__ proj_w, const float* __restrict__ proj_b,
             const float* __restrict__ g_p, const float* __restrict__ b_p,
             const float* __restrict__ w_ff1, const float* __restrict__ bi_ff1,
             const float* __restrict__ w_ff2, const float* __restrict__ bi_ff2,
             const float* __restrict__ w_ta,  const float* __restrict__ bi_ta,
             const float* __restrict__ w_tb,  const float* __restrict__ bi_tb,
             f16* __restrict__ zx)
{
  __shared__ __align__(16) f16   xn_s[16*104];
  __shared__ __align__(16) float fpre_s[16*132];
  __shared__ __align__(16) f16   feat_s[16*136];

  const int tid  = threadIdx.x;
  const int wv   = tid >> 6;
  const int lane = tid & 63;
  const int q    = lane >> 4;
  const int l16  = lane & 15;
  const int jq   = 16*wv + 4*q;

  const float* Wg[4] = { w_ff1, w_ff2, w_ta, w_tb };
  const float* Bg[4] = { bi_ff1, bi_ff2, bi_ta, bi_tb };

  half8 aW1[3];
#pragma unroll
  for (int c = 0; c < 3; ++c)
#pragma unroll
    for (int i = 0; i < 8; ++i){
      int k = 32*c + 8*q + i;
      aW1[c][i] = (k < Dd) ? (f16)proj_w[k*Hh + (16*wv + l16)] : (f16)0.f;
    }
  half8 aW2[4][4];
  f32x4 bias2[4];
#pragma unroll
  for (int g = 0; g < 4; ++g){
    const float* wp = Wg[g];
    const int jc = 16*wv + l16;
#pragma unroll
    for (int c = 0; c < 4; ++c)
#pragma unroll
      for (int i = 0; i < 8; ++i){
        int k = 32*c + 8*q + i;
        aW2[g][c][i] = (f16)wp[k*Hh + jc];
      }
    bias2[g] = *(const f32x4*)(Bg[g] + jq);
  }
  const float gi0 = g_in[lane], bi0 = b_in[lane];
  const float gi1 = (lane < 3) ? g_in[64+lane] : 0.f;
  const float bi1 = (lane < 3) ? b_in[64+lane] : 0.f;
  const float gp0 = g_p[lane],  bp0 = b_p[lane];
  const float gp1 = g_p[64+lane], bp1 = b_p[64+lane];
  const float pb0 = proj_b[lane], pb1 = proj_b[64+lane];

  for (int idx = tid; idx < 16*104; idx += 512)
    if ((idx % 104) >= Dd) xn_s[idx] = (f16)0.f;
  __syncthreads();

  const int wg   = blockIdx.x;
  const int b    = wg >> 2;
  const int t0wg = (wg & 3) * 1024;

  for (int it = 0; it < 64; ++it){
    const int tl0 = t0wg + it*16;
#pragma unroll
    for (int hf = 0; hf < 2; ++hf){
      const int ts = wv + 8*hf;
      const float* xr = x + (size_t)(b*Tt + tl0 + ts) * Dd;
      float v0 = xr[lane];
      float v1 = (lane < 3) ? xr[64+lane] : 0.f;
      float s = v0 + v1, qq = v0*v0 + v1*v1;
      red2(s, qq);
      float mu = s * (1.0f/Dd);
      float rstd = rsqrtf(qq * (1.0f/Dd) - mu*mu + 1e-5f);
      xn_s[ts*104 + lane] = (f16)((v0 - mu)*rstd*gi0 + bi0);
      if (lane < 3) xn_s[ts*104 + 64 + lane] = (f16)((v1 - mu)*rstd*gi1 + bi1);
    }
    __syncthreads();
    {
      f32x4 acc = {0.f, 0.f, 0.f, 0.f};
#pragma unroll
      for (int c = 0; c < 3; ++c){
        half8 bf = *(const half8*)(xn_s + l16*104 + 32*c + 8*q);
        acc = MFMA16(aW1[c], bf, acc);
      }
      *(f32x4*)(fpre_s + l16*132 + jq) = acc;
    }
    __syncthreads();
#pragma unroll
    for (int hf = 0; hf < 2; ++hf){
      const int ts = wv + 8*hf;
      float v0 = fpre_s[ts*132 + lane]      + pb0;
      float v1 = fpre_s[ts*132 + 64 + lane] + pb1;
      float s = v0 + v1, qq = v0*v0 + v1*v1;
      red2(s, qq);
      float mu = s * (1.0f/Hh);
      float rstd = rsqrtf(qq * (1.0f/Hh) - mu*mu + 1e-5f);
      float f0 = (v0 - mu)*rstd*gp0 + bp0;
      float f1 = (v1 - mu)*rstd*gp1 + bp1;
      f0 *= fast_rcp(1.0f + fast_ex2(-L2E*f0));
      f1 *= fast_rcp(1.0f + fast_ex2(-L2E*f1));
      feat_s[ts*136 + lane]      = (f16)f0;
      feat_s[ts*136 + 64 + lane] = (f16)f1;
    }
    __syncthreads();
    {
      half8 bf2[4];
#pragma unroll
      for (int c = 0; c < 4; ++c)
        bf2[c] = *(const half8*)(feat_s + l16*136 + 32*c + 8*q);
      const size_t trow = (size_t)(b*Tt + tl0 + l16) * 512;
      f32x4 accs2[4];
#pragma unroll
      for (int g = 0; g < 4; ++g){
        f32x4 acc = bias2[g];
#pragma unroll
        for (int c = 0; c < 4; ++c)
          acc = MFMA16(aW2[g][c], bf2[c], acc);
        accs2[g] = acc;
      }
#pragma unroll
      for (int r = 0; r < 4; ++r){
        U2 u;
#pragma unroll
        for (int g = 0; g < 4; ++g) u.h[g] = (f16)accs2[g][r];
        const int zoff = ((wv>>1)*128) + ((4*q + r)*8) + ((wv&1)*4);
        *(uint2*)(zx + trow + zoff) = u.u;
      }
    }
    __syncthreads();
  }
}

// ---------------------------------------------------------------------------
// Scan v8: batch-packed MFMA. 4 blocks x 512 thr (8 waves). Block sb owns
// batches sb*16..sb*16+15. A = h[16 batches] (M-dim = batch, no row waste),
// B = W_bot[k][j] VGPR-resident, C rows = batches, C init = z (+bias, baked
// in by stage_a). Wave w8 covers j = 16*w8 + l16. Lane (q,l16) finalizes
// cells for batches 4q+r at j = 16*w8+l16 (4 cells/lane). h exchanged via
// 8-slot XOR-swizzled LDS ring; ring dumped to z region every 8 steps for
// head_k. z and dt register-prefetched 1 step ahead (drain << step time).
// ---------------------------------------------------------------------------
#define SCAN_STEP(T, ZC, DC, ZN, DN)                                           \
  {                                                                            \
    const int t_  = (T);                                                       \
    const int tn_ = (t_+1 < Tt) ? t_+1 : t_;                                   \
    _Pragma("unroll")                                                          \
    for (int r = 0; r < 4; ++r){                                               \
      ZN[r] = *(const uint2*)(zx + zb[r] + (size_t)tn_*512);                   \
      DN[r] = dtp[r][tn_] * 10.0f;                                             \
    }                                                                          \
    const char* hs = (const char*)&hist[(t_+7)&7][0];                          \
    half8 af[4];                                                               \
    _Pragma("unroll")                                                          \
    for (int cc = 0; cc < 4; ++cc)                                             \
      af[cc] = *(const half8*)(hs + afo[cc]);                                  \
    U2 uz0, uz1, uz2, uz3;                                                     \
    uz0.u = ZC[0]; uz1.u = ZC[1]; uz2.u = ZC[2]; uz3.u = ZC[3];                \
    f32x4 acc[4];                                                              \
    _Pragma("unroll")                                                          \
    for (int g = 0; g < 4; ++g){                                               \
      acc[g][0] = (float)uz0.h[g]; acc[g][1] = (float)uz1.h[g];                \
      acc[g][2] = (float)uz2.h[g]; acc[g][3] = (float)uz3.h[g];                \
    }                                                                          \
    _Pragma("unroll")                                                          \
    for (int cc = 0; cc < 4; ++cc){                                            \
      acc[0] = MFMA16(af[cc], bW[0][cc], acc[0]);                              \
      acc[1] = MFMA16(af[cc], bW[1][cc], acc[1]);                              \
      acc[2] = MFMA16(af[cc], bW[2][cc], acc[2]);                              \
      acc[3] = MFMA16(af[cc], bW[3][cc], acc[3]);                              \
    }                                                                          \
    char* hw = (char*)&hist[t_&7][0];                                          \
    _Pragma("unroll")                                                          \
    for (int r = 0; r < 4; ++r){                                               \
      float p0 = acc[0][r], p1 = acc[1][r], p2 = acc[2][r], p3 = acc[3][r];    \
      float gpre = __builtin_fmaf(p2, DC[r], p3);                              \
      float g_ = fast_rcp(fast_ex2(-L2E*gpre) + 1.0f);                         \
      float u_ = fast_rcp(fast_ex2(L2E2*p0) + 1.0f);                           \
      float v_ = fast_rcp(fast_ex2(L2E2*p1) + 1.0f);                           \
      float a_ = __builtin_fmaf(-2.0f, u_, 1.0f);                              \
      float hn = __builtin_fmaf(2.0f*g_, u_ - v_, a_);                         \
      *(f16*)(hw + hwo[r]) = (f16)hn;                                          \
    }                                                                          \
    __syncthreads();                                                           \
    if ((t_ & 7) == 7){                                                        \
      const int db = lane >> 2;                                                \
      const int jb = (lane & 3) * 32;                                          \
      const char* dsrc = (const char*)&hist[w8][0];                            \
      f16* gdst = zx + (size_t)(sb*16+db)*Tt*512 + (size_t)(t_-7+w8)*512 + jb; \
      _Pragma("unroll")                                                        \
      for (int k = 0; k < 4; ++k){                                             \
        half8 hv = *(const half8*)(dsrc + db*256 + ((jb*2 + 16*k) ^ ((db&7)<<4))); \
        *(half8*)(gdst + 8*k) = hv;                                            \
      }                                                                        \
      __syncthreads();                                                         \
    }                                                                          \
  }

__global__ __launch_bounds__(512, 1)
void scan_k(f16* __restrict__ zx, const float* __restrict__ dt,
            const float* __restrict__ w_ff1, const float* __restrict__ w_ff2,
            const float* __restrict__ w_ta,  const float* __restrict__ w_tb)
{
  __shared__ __align__(16) f16 hist[8][2048];   // 8 slots x [b(16) x 128j] swizzled = 32 KB

  const int tid  = threadIdx.x;
  const int w8   = tid >> 6;
  const int lane = tid & 63;
  const int q    = lane >> 4;
  const int l16  = lane & 15;
  const int sb   = blockIdx.x;                  // 0..3

  const float* Wg[4] = { w_ff1, w_ff2, w_ta, w_tb };

  // B operand: n-col j = 16*w8 + l16, k-rows 128+32cc+8q+i (h-half of cat)
  half8 bW[4][4];
#pragma unroll
  for (int g = 0; g < 4; ++g){
    const float* wp = Wg[g];
    const int jc = 16*w8 + l16;
#pragma unroll
    for (int c = 0; c < 4; ++c)
#pragma unroll
      for (int i = 0; i < 8; ++i)
        bW[g][c][i] = (f16)wp[(128 + 32*c + 8*q + i)*Hh + jc];
  }

  // zero hist ring (slot 7 = h(-1) must be 0)
#pragma unroll
  for (int k = 0; k < 4; ++k)
    ((float4*)&hist[0][0])[k*512 + tid] = make_float4(0.f,0.f,0.f,0.f);

  // per-lane z slot in old layout: zoff(j,g)=(j>>5)*128+(j&15)*8+((j>>4)&1)*4+g
  const int zoff = (w8>>1)*128 + l16*8 + (w8&1)*4;
  size_t zb[4];
  const float* dtp[4];
#pragma unroll
  for (int r = 0; r < 4; ++r){
    const int bg = sb*16 + 4*q + r;
    zb[r]  = (size_t)bg * Tt * 512 + zoff;
    dtp[r] = dt + (size_t)bg * Tt;
  }

  // constant per-lane LDS offsets (XOR swizzle: byte ^= (b&7)<<4 within row)
  int afo[4];   // read: h[b=l16][k=32cc+8q+i], b128
#pragma unroll
  for (int cc = 0; cc < 4; ++cc)
    afo[cc] = l16*256 + ((64*cc + 16*q) ^ ((l16&7)<<4));
  int hwo[4];   // write: h[b=4q+r][j=16w8+l16], b16
#pragma unroll
  for (int r = 0; r < 4; ++r)
    hwo[r] = (4*q+r)*256 + ((2*(16*w8+l16)) ^ (((4*q+r)&7)<<4));

  // prologue: z(0), dt(0)
  uint2 zA[4], zB[4]; float dA[4], dB[4];
#pragma unroll
  for (int r = 0; r < 4; ++r){
    zA[r] = *(const uint2*)(zx + zb[r]);
    dA[r] = dtp[r][0] * 10.0f;
  }
  __syncthreads();

  for (int t2 = 0; t2 < Tt; t2 += 2){
    SCAN_STEP(t2,   zA, dA, zB, dB)
    SCAN_STEP(t2+1, zB, dB, zA, dA)
  }
}

// ---------------------------------------------------------------------------
// Head: out[tok] = h[tok] . head_w + head_b (h fp16 from dumped region).
// ---------------------------------------------------------------------------
__global__ __launch_bounds__(256, 4)
void head_k(const f16* __restrict__ zx, const float* __restrict__ head_w,
            const float* __restrict__ head_b, float* __restrict__ out)
{
  const int tok  = (blockIdx.x << 2) + (threadIdx.x >> 6);
  const int lane = threadIdx.x & 63;
  U1 cv; cv.u = *(const unsigned*)(zx + (size_t)tok*512 + 2*lane);
  float s = (float)cv.h[0]*head_w[2*lane] + (float)cv.h[1]*head_w[2*lane+1];
#pragma unroll
  for (int off = 32; off; off >>= 1) s += __shfl_xor(s, off);
  if (lane == 0) out[tok] = s + head_b[0];
}

extern "C" void kernel_launch(void* const* d_in, const int* in_sizes, int n_in,
                              void* d_out, int out_size, void* d_ws, size_t ws_size,
                              hipStream_t stream)
{
  const float* x       = (const float*)d_in[0];
  const float* dt      = (const float*)d_in[1];
  const float* ln_in_g = (const float*)d_in[2];
  const float* ln_in_b = (const float*)d_in[3];
  const float* proj_w  = (const float*)d_in[4];
  const float* proj_b  = (const float*)d_in[5];
  const float* ln_p_g  = (const float*)d_in[6];
  const float* ln_p_b  = (const float*)d_in[7];
  const float* ff1_w   = (const float*)d_in[8];
  const float* ff1_b   = (const float*)d_in[9];
  const float* ff2_w   = (const float*)d_in[10];
  const float* ff2_b   = (const float*)d_in[11];
  const float* ta_w    = (const float*)d_in[12];
  const float* ta_b    = (const float*)d_in[13];
  const float* tb_w    = (const float*)d_in[14];
  const float* tb_b    = (const float*)d_in[15];
  const float* head_w  = (const float*)d_in[16];
  const float* head_b  = (const float*)d_in[17];

  f16*   zx  = (f16*)d_ws;      // [b][t][512] fp16 = 256 MiB (z, then h)
  float* out = (float*)d_out;

  stage_a<<<dim3(256), dim3(512), 0, stream>>>(
      x, ln_in_g, ln_in_b, proj_w, proj_b, ln_p_g, ln_p_b,
      ff1_w, ff1_b, ff2_w, ff2_b, ta_w, ta_b, tb_w, tb_b, zx);

  scan_k<<<dim3(4), dim3(512), 0, stream>>>(
      zx, dt, ff1_w, ff2_w, ta_w, tb_w);

  head_k<<<dim3(Bb*Tt/4), dim3(256), 0, stream>>>(
      zx, head_w, head_b, out);
}